// Round 1
// baseline (147.984 us; speedup 1.0000x reference)
//
#include <hip/hip_runtime.h>

#define T_SEQ 1024
#define C_DIM 512
#define H_HEADS 8
#define HDIM 64
#define B_BATCH 4
#define M_ROWS (B_BATCH * T_SEQ)   // 4096

typedef __attribute__((ext_vector_type(8))) short short8;
typedef __attribute__((ext_vector_type(4))) float f32x4;

__device__ __forceinline__ unsigned short f2bf(float f) {
    unsigned u = __builtin_bit_cast(unsigned, f);
    u += 0x7FFFu + ((u >> 16) & 1u);   // round-to-nearest-even
    return (unsigned short)(u >> 16);
}

// ---------------------------------------------------------------------------
// Kernel 1: cast x and the 4 weight matrices to bf16 in workspace
// ---------------------------------------------------------------------------
__global__ __launch_bounds__(256) void cast_all(
    const float* __restrict__ x,
    const float* __restrict__ wq, const float* __restrict__ wk,
    const float* __restrict__ wv, const float* __restrict__ wp,
    unsigned short* __restrict__ xb,
    unsigned short* __restrict__ wqb, unsigned short* __restrict__ wkb,
    unsigned short* __restrict__ wvb, unsigned short* __restrict__ wpb)
{
    const long NX = (long)M_ROWS * C_DIM;        // 2,097,152
    const long NW = (long)C_DIM * C_DIM;         // 262,144
    long i4 = (long)blockIdx.x * blockDim.x + threadIdx.x;
    long base = i4 * 4;
    const float* src; unsigned short* dst; long off;
    if (base < NX) { src = x; dst = xb; off = base; }
    else {
        long r = base - NX;
        int w = (int)(r >> 18);            // 262144 elements per weight
        off = r & (NW - 1);
        switch (w) {
            case 0:  src = wq; dst = wqb; break;
            case 1:  src = wk; dst = wkb; break;
            case 2:  src = wv; dst = wvb; break;
            default: src = wp; dst = wpb; break;
        }
    }
    float4 v = *(const float4*)(src + off);
    ushort4 o;
    o.x = f2bf(v.x); o.y = f2bf(v.y); o.z = f2bf(v.z); o.w = f2bf(v.w);
    *(ushort4*)(dst + off) = o;
}

// ---------------------------------------------------------------------------
// Shared GEMM body: O(M x 512) = A(M x 512, bf16) @ W^T(512 x 512, bf16) + b
// BHTD=true : write bf16 into (B,H,T,HD) layout
// BHTD=false: write fp32 row-major (M x 512)
// Tile: 64x64 per block, 256 threads = 4 waves, each wave 16 rows x 64 cols.
// MFMA 16x16x32 bf16. LDS stride 72 (16B-aligned, breaks pow2 banking).
// ---------------------------------------------------------------------------
template <bool BHTD>
__device__ __forceinline__ void gemm_body(
    const unsigned short* __restrict__ A,
    const unsigned short* __restrict__ W,
    const float* __restrict__ bias,
    unsigned short* __restrict__ Obf,
    float* __restrict__ Of)
{
    __shared__ __align__(16) unsigned short Al[64 * 72];
    __shared__ __align__(16) unsigned short Bl[64 * 72];

    const int tid  = threadIdx.x;
    const int w    = tid >> 6;
    const int lane = tid & 63;
    const int quad = lane >> 4;
    const int l16  = lane & 15;
    const int m0   = blockIdx.x * 64;
    const int n0   = blockIdx.y * 64;

    f32x4 acc[4] = {};

    for (int k0 = 0; k0 < 512; k0 += 64) {
        __syncthreads();
        // stage A and B tiles (coalesced 16B chunks)
        for (int it = 0; it < 2; ++it) {
            int ch = tid + 256 * it;          // 0..511
            int r = ch >> 3, c8 = ch & 7;
            *(short8*)&Al[r * 72 + c8 * 8] =
                *(const short8*)&A[(long)(m0 + r) * 512 + k0 + c8 * 8];
            *(short8*)&Bl[r * 72 + c8 * 8] =
                *(const short8*)&W[(long)(n0 + r) * 512 + k0 + c8 * 8];
        }
        __syncthreads();
        for (int s = 0; s < 2; ++s) {
            short8 af = *(const short8*)&Al[(16 * w + l16) * 72 + 32 * s + 8 * quad];
            for (int ct = 0; ct < 4; ++ct) {
                short8 bf = *(const short8*)&Bl[(16 * ct + l16) * 72 + 32 * s + 8 * quad];
                acc[ct] = __builtin_amdgcn_mfma_f32_16x16x32_bf16(af, bf, acc[ct], 0, 0, 0);
            }
        }
    }

    // epilogue: D layout col = lane&15, row = 4*quad + reg
    for (int ct = 0; ct < 4; ++ct) {
        int col = n0 + 16 * ct + l16;
        float bv = bias[col];
        for (int reg = 0; reg < 4; ++reg) {
            int row = m0 + 16 * w + 4 * quad + reg;
            float v = acc[ct][reg] + bv;
            if (BHTD) {
                int b = row >> 10, t = row & 1023;
                int h = col >> 6,  hd = col & 63;
                Obf[(((long)(b * H_HEADS + h)) * T_SEQ + t) * HDIM + hd] = f2bf(v);
            } else {
                Of[(long)row * 512 + col] = v;
            }
        }
    }
}

__global__ __launch_bounds__(256) void gemm_qkv(
    const unsigned short* __restrict__ A,
    const unsigned short* __restrict__ Wq, const unsigned short* __restrict__ Wk,
    const unsigned short* __restrict__ Wv,
    const float* __restrict__ bq, const float* __restrict__ bk, const float* __restrict__ bv,
    unsigned short* __restrict__ Q, unsigned short* __restrict__ K,
    unsigned short* __restrict__ V)
{
    const unsigned short* W; const float* b; unsigned short* O;
    if (blockIdx.z == 0)      { W = Wq; b = bq; O = Q; }
    else if (blockIdx.z == 1) { W = Wk; b = bk; O = K; }
    else                      { W = Wv; b = bv; O = V; }
    gemm_body<true>(A, W, b, O, nullptr);
}

__global__ __launch_bounds__(256) void gemm_out_k(
    const unsigned short* __restrict__ A, const unsigned short* __restrict__ W,
    const float* __restrict__ bias, float* __restrict__ O)
{
    gemm_body<false>(A, W, bias, nullptr, O);
}

// ---------------------------------------------------------------------------
// Kernel 3: flash attention with online softmax.
// Block: 256 threads (4 waves). BQ=64 q rows per block, wave w owns rows
// [16w,16w+16). Iterate BK=64 key tiles up to the causal limit.
// Q,K,V in (B,H,T,HD) bf16. Output Y bf16 in (B,T,C) layout.
// ---------------------------------------------------------------------------
__global__ __launch_bounds__(256) void attn(
    const unsigned short* __restrict__ Q, const unsigned short* __restrict__ K,
    const unsigned short* __restrict__ V, const float* __restrict__ attn_bias,
    unsigned short* __restrict__ Y)
{
    __shared__ __align__(16) unsigned short Kl[64 * 72];
    __shared__ __align__(16) unsigned short Vt[64 * 72];       // transposed: [hd][key]
    __shared__ __align__(16) unsigned short Pl[4][16 * 72];    // per-wave P
    __shared__ float biasl[8][64];                             // node bias rows

    const int tid  = threadIdx.x;
    const int w    = tid >> 6;
    const int lane = tid & 63;
    const int quad = lane >> 4;
    const int l16  = lane & 15;
    const int bx   = blockIdx.x;        // q tile index
    const int bh   = blockIdx.y;        // b*H + h
    const int h    = bh & 7;
    const int q0   = bx * 64;

    // preload the 8 node-bias rows this q-tile needs (only if q0 < 512)
    if (q0 < 512) {
        for (int i = tid; i < 512; i += 256) {
            int nq = (q0 >> 3) + (i >> 6);
            biasl[i >> 6][i & 63] = attn_bias[h * 4096 + nq * 64 + (i & 63)];
        }
    }

    const unsigned short* Qbh = Q + (long)bh * T_SEQ * HDIM;
    const unsigned short* Kbh = K + (long)bh * T_SEQ * HDIM;
    const unsigned short* Vbh = V + (long)bh * T_SEQ * HDIM;

    // Q fragments held in registers across the whole key loop
    short8 qf[2];
    {
        int qr = q0 + 16 * w + l16;
        qf[0] = *(const short8*)&Qbh[(long)qr * HDIM + 8 * quad];
        qf[1] = *(const short8*)&Qbh[(long)qr * HDIM + 32 + 8 * quad];
    }

    f32x4 oacc[4] = {};
    float mrow[4] = {-INFINITY, -INFINITY, -INFINITY, -INFINITY};
    float lrow[4] = {0.f, 0.f, 0.f, 0.f};

    const int ntiles = bx + 1;
    for (int kt = 0; kt < ntiles; ++kt) {
        const int k0 = kt * 64;
        __syncthreads();    // all waves done reading Kl/Vt from prev iter
        // stage K (coalesced)
        for (int it = 0; it < 2; ++it) {
            int ch = tid + 256 * it;
            int r = ch >> 3, c8 = ch & 7;
            *(short8*)&Kl[r * 72 + c8 * 8] =
                *(const short8*)&Kbh[(long)(k0 + r) * HDIM + c8 * 8];
        }
        // stage V transposed: lane maps to key index r -> conflict-free LDS writes
        for (int it = 0; it < 2; ++it) {
            int ch = tid + 256 * it;
            int r = ch & 63, c8 = ch >> 6;
            short8 v = *(const short8*)&Vbh[(long)(k0 + r) * HDIM + c8 * 8];
            for (int j = 0; j < 8; ++j)
                Vt[(c8 * 8 + j) * 72 + r] = (unsigned short)v[j];
        }
        __syncthreads();

        // S = Q K^T  (16 x 64 per wave)
        f32x4 s[4] = {};
        for (int st = 0; st < 2; ++st) {
            for (int ct = 0; ct < 4; ++ct) {
                short8 bf = *(const short8*)&Kl[(16 * ct + l16) * 72 + 32 * st + 8 * quad];
                s[ct] = __builtin_amdgcn_mfma_f32_16x16x32_bf16(qf[st], bf, s[ct], 0, 0, 0);
            }
        }

        // scale + bias + mask, track row max
        const int qrb = q0 + 16 * w + 4 * quad;   // + reg
        float rmax[4] = {-INFINITY, -INFINITY, -INFINITY, -INFINITY};
        for (int ct = 0; ct < 4; ++ct) {
            int kcol = k0 + 16 * ct + l16;
            for (int reg = 0; reg < 4; ++reg) {
                int qrow = qrb + reg;
                float v = s[ct][reg] * 0.125f;
                if (qrow < 512 && kcol < 512)
                    v += biasl[(qrow >> 3) & 7][kcol >> 3];
                bool keep = (kcol <= qrow) && ((kcol & 15) != 15);
                v = keep ? v : -INFINITY;
                s[ct][reg] = v;
                rmax[reg] = fmaxf(rmax[reg], v);
            }
        }
        // reduce row max across the 16 lanes of each quad
        for (int off = 1; off < 16; off <<= 1)
            for (int reg = 0; reg < 4; ++reg)
                rmax[reg] = fmaxf(rmax[reg], __shfl_xor(rmax[reg], off));

        float alpha[4];
        for (int reg = 0; reg < 4; ++reg) {
            float mnew = fmaxf(mrow[reg], rmax[reg]);
            alpha[reg] = __expf(mrow[reg] - mnew);   // exp(-inf)=0 on first tile
            mrow[reg] = mnew;
        }

        // P = exp(S - m), write to per-wave LDS (D layout -> rows)
        float rsum[4] = {0.f, 0.f, 0.f, 0.f};
        for (int ct = 0; ct < 4; ++ct) {
            for (int reg = 0; reg < 4; ++reg) {
                float p = __expf(s[ct][reg] - mrow[reg]);
                rsum[reg] += p;
                Pl[w][(4 * quad + reg) * 72 + 16 * ct + l16] = f2bf(p);
            }
        }
        for (int off = 1; off < 16; off <<= 1)
            for (int reg = 0; reg < 4; ++reg)
                rsum[reg] += __shfl_xor(rsum[reg], off);
        for (int reg = 0; reg < 4; ++reg)
            lrow[reg] = lrow[reg] * alpha[reg] + rsum[reg];
        for (int ct = 0; ct < 4; ++ct)
            for (int reg = 0; reg < 4; ++reg)
                oacc[ct][reg] *= alpha[reg];

        // O += P V   (P read back in A layout: [m=l16][k=8*quad+j])
        for (int st = 0; st < 2; ++st) {
            short8 af = *(const short8*)&Pl[w][l16 * 72 + 32 * st + 8 * quad];
            for (int ct = 0; ct < 4; ++ct) {
                short8 bf = *(const short8*)&Vt[(16 * ct + l16) * 72 + 32 * st + 8 * quad];
                oacc[ct] = __builtin_amdgcn_mfma_f32_16x16x32_bf16(af, bf, oacc[ct], 0, 0, 0);
            }
        }
    }

    // epilogue: Y in (B,T,C) bf16, normalize by l
    const int b = bh >> 3;
    for (int ct = 0; ct < 4; ++ct) {
        int hd = 16 * ct + l16;
        for (int reg = 0; reg < 4; ++reg) {
            int qrow = q0 + 16 * w + 4 * quad + reg;
            float o = oacc[ct][reg] / lrow[reg];
            Y[((long)b * T_SEQ + qrow) * C_DIM + h * HDIM + hd] = f2bf(o);
        }
    }
}

// ---------------------------------------------------------------------------
extern "C" void kernel_launch(void* const* d_in, const int* in_sizes, int n_in,
                              void* d_out, int out_size, void* d_ws, size_t ws_size,
                              hipStream_t stream)
{
    const float* x         = (const float*)d_in[0];
    const float* attn_bias = (const float*)d_in[1];
    const float* Wq = (const float*)d_in[2]; const float* bq = (const float*)d_in[3];
    const float* Wk = (const float*)d_in[4]; const float* bk = (const float*)d_in[5];
    const float* Wv = (const float*)d_in[6]; const float* bv = (const float*)d_in[7];
    const float* Wp = (const float*)d_in[8]; const float* bp = (const float*)d_in[9];
    float* out = (float*)d_out;

    const long NX = (long)M_ROWS * C_DIM;    // 2,097,152
    const long NW = (long)C_DIM * C_DIM;     // 262,144

    unsigned short* xb  = (unsigned short*)d_ws;
    unsigned short* wqb = xb  + NX;
    unsigned short* wkb = wqb + NW;
    unsigned short* wvb = wkb + NW;
    unsigned short* wpb = wvb + NW;
    unsigned short* Qb  = wpb + NW;
    unsigned short* Kb  = Qb  + NX;
    unsigned short* Vb  = Kb  + NX;
    unsigned short* Yb  = Vb  + NX;
    // total: 5*NX + 4*NW shorts = ~22 MiB

    // 1) cast inputs to bf16
    long n4 = (NX + 4 * NW) / 4;             // 786,432 float4 groups
    cast_all<<<dim3((unsigned)(n4 / 256)), 256, 0, stream>>>(
        x, Wq, Wk, Wv, Wp, xb, wqb, wkb, wvb, wpb);

    // 2) QKV projections (z selects Q/K/V)
    gemm_qkv<<<dim3(M_ROWS / 64, C_DIM / 64, 3), 256, 0, stream>>>(
        xb, wqb, wkb, wvb, bq, bk, bv, Qb, Kb, Vb);

    // 3) attention
    attn<<<dim3(T_SEQ / 64, B_BATCH * H_HEADS), 256, 0, stream>>>(
        Qb, Kb, Vb, attn_bias, Yb);

    // 4) output projection -> fp32 out
    gemm_out_k<<<dim3(M_ROWS / 64, C_DIM / 64), 256, 0, stream>>>(
        Yb, wpb, bp, out);
}

// Round 2
// 142.570 us; speedup vs baseline: 1.0380x; 1.0380x over previous
//
#include <hip/hip_runtime.h>

#define T_SEQ 1024
#define C_DIM 512
#define H_HEADS 8
#define HDIM 64
#define B_BATCH 4
#define M_ROWS (B_BATCH * T_SEQ)   // 4096
#define NSPLIT_TOT 40              // sum over bx of ceil((bx+1)/4)

typedef __attribute__((ext_vector_type(8))) short short8;
typedef __attribute__((ext_vector_type(4))) float f32x4;

__device__ __forceinline__ unsigned short f2bf(float f) {
    unsigned u = __builtin_bit_cast(unsigned, f);
    u += 0x7FFFu + ((u >> 16) & 1u);   // round-to-nearest-even
    return (unsigned short)(u >> 16);
}

// split-index -> (q-tile, split) tables; CUM_OF[bx] = first split index of q-tile bx
__device__ __constant__ unsigned char BX_OF[NSPLIT_TOT] =
    {0,1,2,3,4,4,5,5,6,6,7,7,8,8,8,9,9,9,10,10,10,11,11,11,
     12,12,12,12,13,13,13,13,14,14,14,14,15,15,15,15};
__device__ __constant__ unsigned char SP_OF[NSPLIT_TOT] =
    {0,0,0,0,0,1,0,1,0,1,0,1,0,1,2,0,1,2,0,1,2,0,1,2,
     0,1,2,3,0,1,2,3,0,1,2,3,0,1,2,3};
__device__ __constant__ unsigned char CUM_OF[16] =
    {0,1,2,3,4,6,8,10,12,15,18,21,24,28,32,36};

// ---------------------------------------------------------------------------
// Kernel 1: cast x and the 4 weight matrices to bf16 in workspace
// ---------------------------------------------------------------------------
__global__ __launch_bounds__(256) void cast_all(
    const float* __restrict__ x,
    const float* __restrict__ wq, const float* __restrict__ wk,
    const float* __restrict__ wv, const float* __restrict__ wp,
    unsigned short* __restrict__ xb,
    unsigned short* __restrict__ wqb, unsigned short* __restrict__ wkb,
    unsigned short* __restrict__ wvb, unsigned short* __restrict__ wpb)
{
    const long NX = (long)M_ROWS * C_DIM;
    const long NW = (long)C_DIM * C_DIM;
    long i4 = (long)blockIdx.x * blockDim.x + threadIdx.x;
    long base = i4 * 4;
    const float* src; unsigned short* dst; long off;
    if (base < NX) { src = x; dst = xb; off = base; }
    else {
        long r = base - NX;
        int w = (int)(r >> 18);
        off = r & (NW - 1);
        switch (w) {
            case 0:  src = wq; dst = wqb; break;
            case 1:  src = wk; dst = wkb; break;
            case 2:  src = wv; dst = wvb; break;
            default: src = wp; dst = wpb; break;
        }
    }
    float4 v = *(const float4*)(src + off);
    ushort4 o;
    o.x = f2bf(v.x); o.y = f2bf(v.y); o.z = f2bf(v.z); o.w = f2bf(v.w);
    *(ushort4*)(dst + off) = o;
}

// ---------------------------------------------------------------------------
// Shared GEMM body: O(M x 512) = A(M x 512, bf16) @ W^T(512 x 512, bf16) + b
// mode 0: write bf16 (B,H,T,HD);  mode 1: write bf16 (B,H,HD,T) [V^T];
// mode 2: write fp32 row-major (M x 512)
// ---------------------------------------------------------------------------
__device__ __forceinline__ void gemm_body(
    const unsigned short* __restrict__ A,
    const unsigned short* __restrict__ W,
    const float* __restrict__ bias,
    unsigned short* __restrict__ Obf,
    float* __restrict__ Of,
    int mode)
{
    __shared__ __align__(16) unsigned short Al[64 * 72];
    __shared__ __align__(16) unsigned short Bl[64 * 72];

    const int tid  = threadIdx.x;
    const int w    = tid >> 6;
    const int lane = tid & 63;
    const int quad = lane >> 4;
    const int l16  = lane & 15;
    const int m0   = blockIdx.x * 64;
    const int n0   = blockIdx.y * 64;

    f32x4 acc[4] = {};

    for (int k0 = 0; k0 < 512; k0 += 64) {
        __syncthreads();
        for (int it = 0; it < 2; ++it) {
            int ch = tid + 256 * it;
            int r = ch >> 3, c8 = ch & 7;
            *(short8*)&Al[r * 72 + c8 * 8] =
                *(const short8*)&A[(long)(m0 + r) * 512 + k0 + c8 * 8];
            *(short8*)&Bl[r * 72 + c8 * 8] =
                *(const short8*)&W[(long)(n0 + r) * 512 + k0 + c8 * 8];
        }
        __syncthreads();
        for (int s = 0; s < 2; ++s) {
            short8 af = *(const short8*)&Al[(16 * w + l16) * 72 + 32 * s + 8 * quad];
            for (int ct = 0; ct < 4; ++ct) {
                short8 bf = *(const short8*)&Bl[(16 * ct + l16) * 72 + 32 * s + 8 * quad];
                acc[ct] = __builtin_amdgcn_mfma_f32_16x16x32_bf16(af, bf, acc[ct], 0, 0, 0);
            }
        }
    }

    for (int ct = 0; ct < 4; ++ct) {
        int col = n0 + 16 * ct + l16;
        float bv = bias[col];
        for (int reg = 0; reg < 4; ++reg) {
            int row = m0 + 16 * w + 4 * quad + reg;
            float v = acc[ct][reg] + bv;
            if (mode == 2) {
                Of[(long)row * 512 + col] = v;
            } else {
                int b = row >> 10, t = row & 1023;
                int h = col >> 6,  hd = col & 63;
                long idx = (mode == 0)
                    ? ((((long)(b * H_HEADS + h)) * T_SEQ + t) * HDIM + hd)
                    : ((((long)(b * H_HEADS + h)) * HDIM + hd) * T_SEQ + t);
                Obf[idx] = f2bf(v);
            }
        }
    }
}

__global__ __launch_bounds__(256) void gemm_qkv(
    const unsigned short* __restrict__ A,
    const unsigned short* __restrict__ Wq, const unsigned short* __restrict__ Wk,
    const unsigned short* __restrict__ Wv,
    const float* __restrict__ bq, const float* __restrict__ bk, const float* __restrict__ bv,
    unsigned short* __restrict__ Q, unsigned short* __restrict__ K,
    unsigned short* __restrict__ V)
{
    const unsigned short* W; const float* b; unsigned short* O; int mode;
    if (blockIdx.z == 0)      { W = Wq; b = bq; O = Q; mode = 0; }
    else if (blockIdx.z == 1) { W = Wk; b = bk; O = K; mode = 0; }
    else                      { W = Wv; b = bv; O = V; mode = 1; }
    gemm_body(A, W, b, O, nullptr, mode);
}

__global__ __launch_bounds__(256) void gemm_out_k(
    const unsigned short* __restrict__ A, const unsigned short* __restrict__ W,
    const float* __restrict__ bias, float* __restrict__ O)
{
    gemm_body(A, W, bias, nullptr, O, 2);
}

// ---------------------------------------------------------------------------
// Kernel 3a: split-K flash attention. Each block = one (bh, q-tile, split).
// Split covers up to 4 key tiles (256 keys). Writes unnormalized partial
// O (fp32), m, l for the combine pass. V input is pre-transposed (B,H,HD,T).
// ---------------------------------------------------------------------------
__global__ __launch_bounds__(256) void attn_split(
    const unsigned short* __restrict__ Q, const unsigned short* __restrict__ K,
    const unsigned short* __restrict__ Vt, const float* __restrict__ attn_bias,
    float* __restrict__ Opart, float* __restrict__ mpart, float* __restrict__ lpart)
{
    __shared__ __align__(16) unsigned short Kl[64 * 72];
    __shared__ __align__(16) unsigned short Vl[64 * 72];     // [hd][key]
    __shared__ __align__(16) unsigned short Pl[4][16 * 72];
    __shared__ float biasl[8][64];

    const int tid  = threadIdx.x;
    const int w    = tid >> 6;
    const int lane = tid & 63;
    const int quad = lane >> 4;
    const int l16  = lane & 15;
    const int sidx = blockIdx.x;
    const int bh   = blockIdx.y;
    const int h    = bh & 7;
    const int bx   = BX_OF[sidx];
    const int sp   = SP_OF[sidx];
    const int q0   = bx * 64;
    const int kt0  = sp * 4;
    const int kt1  = min(kt0 + 4, bx + 1);

    if (q0 < 512 && sp < 2) {
        for (int i = tid; i < 512; i += 256) {
            int nq = (q0 >> 3) + (i >> 6);
            biasl[i >> 6][i & 63] = attn_bias[h * 4096 + nq * 64 + (i & 63)];
        }
    }

    const unsigned short* Qbh = Q  + (long)bh * T_SEQ * HDIM;
    const unsigned short* Kbh = K  + (long)bh * T_SEQ * HDIM;
    const unsigned short* Vbh = Vt + (long)bh * HDIM * T_SEQ;   // [hd][t]

    short8 qf[2];
    {
        int qr = q0 + 16 * w + l16;
        qf[0] = *(const short8*)&Qbh[(long)qr * HDIM + 8 * quad];
        qf[1] = *(const short8*)&Qbh[(long)qr * HDIM + 32 + 8 * quad];
    }

    f32x4 oacc[4] = {};
    float mrow[4] = {-INFINITY, -INFINITY, -INFINITY, -INFINITY};
    float lrow[4] = {0.f, 0.f, 0.f, 0.f};

    for (int kt = kt0; kt < kt1; ++kt) {
        const int k0 = kt * 64;
        __syncthreads();
        // stage K tile [key][hd] and V tile [hd][key] (both vector 16B)
        for (int it = 0; it < 2; ++it) {
            int ch = tid + 256 * it;
            int r = ch >> 3, c8 = ch & 7;
            *(short8*)&Kl[r * 72 + c8 * 8] =
                *(const short8*)&Kbh[(long)(k0 + r) * HDIM + c8 * 8];
            *(short8*)&Vl[r * 72 + c8 * 8] =
                *(const short8*)&Vbh[(long)r * T_SEQ + k0 + c8 * 8];
        }
        __syncthreads();

        // S = Q K^T  (16 x 64 per wave)
        f32x4 s[4] = {};
        for (int st = 0; st < 2; ++st) {
            for (int ct = 0; ct < 4; ++ct) {
                short8 bf = *(const short8*)&Kl[(16 * ct + l16) * 72 + 32 * st + 8 * quad];
                s[ct] = __builtin_amdgcn_mfma_f32_16x16x32_bf16(qf[st], bf, s[ct], 0, 0, 0);
            }
        }

        const int qrb = q0 + 16 * w + 4 * quad;
        float rmax[4] = {-INFINITY, -INFINITY, -INFINITY, -INFINITY};
        for (int ct = 0; ct < 4; ++ct) {
            int kcol = k0 + 16 * ct + l16;
            for (int reg = 0; reg < 4; ++reg) {
                int qrow = qrb + reg;
                float v = s[ct][reg] * 0.125f;
                if (qrow < 512 && kcol < 512)
                    v += biasl[(qrow >> 3) & 7][kcol >> 3];
                bool keep = (kcol <= qrow) && ((kcol & 15) != 15);
                v = keep ? v : -INFINITY;
                s[ct][reg] = v;
                rmax[reg] = fmaxf(rmax[reg], v);
            }
        }
        for (int off = 1; off < 16; off <<= 1)
            for (int reg = 0; reg < 4; ++reg)
                rmax[reg] = fmaxf(rmax[reg], __shfl_xor(rmax[reg], off));

        float alpha[4];
        for (int reg = 0; reg < 4; ++reg) {
            float mnew = fmaxf(mrow[reg], rmax[reg]);
            alpha[reg] = __expf(mrow[reg] - mnew);
            mrow[reg] = mnew;
        }

        float rsum[4] = {0.f, 0.f, 0.f, 0.f};
        for (int ct = 0; ct < 4; ++ct) {
            for (int reg = 0; reg < 4; ++reg) {
                float p = __expf(s[ct][reg] - mrow[reg]);
                rsum[reg] += p;
                Pl[w][(4 * quad + reg) * 72 + 16 * ct + l16] = f2bf(p);
            }
        }
        for (int off = 1; off < 16; off <<= 1)
            for (int reg = 0; reg < 4; ++reg)
                rsum[reg] += __shfl_xor(rsum[reg], off);
        for (int reg = 0; reg < 4; ++reg)
            lrow[reg] = lrow[reg] * alpha[reg] + rsum[reg];
        for (int ct = 0; ct < 4; ++ct)
            for (int reg = 0; reg < 4; ++reg)
                oacc[ct][reg] *= alpha[reg];

        for (int st = 0; st < 2; ++st) {
            short8 af = *(const short8*)&Pl[w][l16 * 72 + 32 * st + 8 * quad];
            for (int ct = 0; ct < 4; ++ct) {
                short8 bf = *(const short8*)&Vl[(16 * ct + l16) * 72 + 32 * st + 8 * quad];
                oacc[ct] = __builtin_amdgcn_mfma_f32_16x16x32_bf16(af, bf, oacc[ct], 0, 0, 0);
            }
        }
    }

    // partial epilogue (unnormalized)
    const long p = (long)bh * NSPLIT_TOT + sidx;
    float* Op = Opart + p * 4096;
    for (int ct = 0; ct < 4; ++ct)
        for (int reg = 0; reg < 4; ++reg)
            Op[(16 * w + 4 * quad + reg) * 64 + 16 * ct + l16] = oacc[ct][reg];
    if (l16 == 0) {
        for (int reg = 0; reg < 4; ++reg) {
            int qr = 16 * w + 4 * quad + reg;
            mpart[p * 64 + qr] = mrow[reg];
            lpart[p * 64 + qr] = lrow[reg];
        }
    }
}

// ---------------------------------------------------------------------------
// Kernel 3b: combine splits, normalize, write Y bf16 (B,T,C)
// ---------------------------------------------------------------------------
__global__ __launch_bounds__(256) void attn_combine(
    const float* __restrict__ Opart, const float* __restrict__ mpart,
    const float* __restrict__ lpart, unsigned short* __restrict__ Y)
{
    const int bx = blockIdx.x, bh = blockIdx.y;
    const int b = bh >> 3, h = bh & 7;
    const int ns = (bx >> 2) + 1;
    const long p0 = (long)bh * NSPLIT_TOT + CUM_OF[bx];
    const int tid = threadIdx.x;
    const int qr = tid >> 2;
    const int hs = (tid & 3) * 16;

    float m[4], l[4];
    for (int s = 0; s < ns; ++s) {
        m[s] = mpart[(p0 + s) * 64 + qr];
        l[s] = lpart[(p0 + s) * 64 + qr];
    }
    float ms = -INFINITY;
    for (int s = 0; s < ns; ++s) ms = fmaxf(ms, m[s]);
    float L = 0.f, sc[4];
    for (int s = 0; s < ns; ++s) { sc[s] = __expf(m[s] - ms); L += l[s] * sc[s]; }

    float acc[16] = {};
    for (int s = 0; s < ns; ++s) {
        const float4* op = (const float4*)(Opart + (p0 + s) * 4096 + qr * 64 + hs);
        float f = sc[s];
        for (int j4 = 0; j4 < 4; ++j4) {
            float4 v = op[j4];
            acc[4 * j4 + 0] += f * v.x; acc[4 * j4 + 1] += f * v.y;
            acc[4 * j4 + 2] += f * v.z; acc[4 * j4 + 3] += f * v.w;
        }
    }
    float inv = 1.f / L;
    int q = bx * 64 + qr;
    unsigned short* y = Y + ((long)b * T_SEQ + q) * C_DIM + h * HDIM + hs;
    for (int j4 = 0; j4 < 4; ++j4) {
        ushort4 o;
        o.x = f2bf(acc[4 * j4 + 0] * inv); o.y = f2bf(acc[4 * j4 + 1] * inv);
        o.z = f2bf(acc[4 * j4 + 2] * inv); o.w = f2bf(acc[4 * j4 + 3] * inv);
        *(ushort4*)(y + 4 * j4) = o;
    }
}

// ---------------------------------------------------------------------------
extern "C" void kernel_launch(void* const* d_in, const int* in_sizes, int n_in,
                              void* d_out, int out_size, void* d_ws, size_t ws_size,
                              hipStream_t stream)
{
    const float* x         = (const float*)d_in[0];
    const float* attn_bias = (const float*)d_in[1];
    const float* Wq = (const float*)d_in[2]; const float* bq = (const float*)d_in[3];
    const float* Wk = (const float*)d_in[4]; const float* bk = (const float*)d_in[5];
    const float* Wv = (const float*)d_in[6]; const float* bv = (const float*)d_in[7];
    const float* Wp = (const float*)d_in[8]; const float* bp = (const float*)d_in[9];
    float* out = (float*)d_out;

    const long NX = (long)M_ROWS * C_DIM;    // 2,097,152
    const long NW = (long)C_DIM * C_DIM;     // 262,144

    unsigned short* xb  = (unsigned short*)d_ws;
    unsigned short* wqb = xb  + NX;
    unsigned short* wkb = wqb + NW;
    unsigned short* wvb = wkb + NW;
    unsigned short* wpb = wvb + NW;
    unsigned short* Qb  = wpb + NW;
    unsigned short* Kb  = Qb  + NX;
    unsigned short* Vtb = Kb  + NX;          // transposed (B,H,HD,T)
    unsigned short* Yb  = Vtb + NX;
    float* Opart = (float*)(Yb + NX);        // 32*40 tiles x 64x64 fp32 = 21 MB
    float* mpart = Opart + (long)32 * NSPLIT_TOT * 4096;
    float* lpart = mpart + (long)32 * NSPLIT_TOT * 64;
    // total ~45 MB

    long n4 = (NX + 4 * NW) / 4;
    cast_all<<<dim3((unsigned)(n4 / 256)), 256, 0, stream>>>(
        x, Wq, Wk, Wv, Wp, xb, wqb, wkb, wvb, wpb);

    gemm_qkv<<<dim3(M_ROWS / 64, C_DIM / 64, 3), 256, 0, stream>>>(
        xb, wqb, wkb, wvb, bq, bk, bv, Qb, Kb, Vtb);

    attn_split<<<dim3(NSPLIT_TOT, B_BATCH * H_HEADS), 256, 0, stream>>>(
        Qb, Kb, Vtb, attn_bias, Opart, mpart, lpart);

    attn_combine<<<dim3(T_SEQ / 64, B_BATCH * H_HEADS), 256, 0, stream>>>(
        Opart, mpart, lpart, Yb);

    gemm_out_k<<<dim3(M_ROWS / 64, C_DIM / 64), 256, 0, stream>>>(
        Yb, wpb, bp, out);
}